// Round 16
// baseline (3611.382 us; speedup 1.0000x reference)
//
#include <hip/hip_runtime.h>
#include <hip/hip_cooperative_groups.h>

// TwoStreamNet on MI355X — f32 I/O, bf16 MFMA internals.
// R16: persistent cooperative mega-kernel (512 co-resident blocks, grid.sync
//      between the 23 post-prep phases) replaces ~23 launch boundaries.
//      Classic R15 launch sequence kept as verified fallback.

namespace cg = cooperative_groups;

typedef short short8 __attribute__((ext_vector_type(8)));
typedef float floatx4 __attribute__((ext_vector_type(4)));
typedef unsigned short ushort4v __attribute__((ext_vector_type(4)));
typedef unsigned short u16;

#define DIMN 256
#define GBK 64

static const int kNV = 6144;
static const int kNF = 12288;
static const int SLAB = 768;

__device__ __forceinline__ float bf2f(u16 u) {
  union { unsigned int i; float f; } x; x.i = ((unsigned int)u) << 16; return x.f;
}
__device__ __forceinline__ u16 f2bf(float f) {
  union { float f; unsigned int i; } x; x.f = f;
  unsigned int r = x.i + 0x7fffu + ((x.i >> 16) & 1u);
  return (u16)(r >> 16);
}
__device__ __forceinline__ void gld_lds16(const void* g, void* l) {
  __builtin_amdgcn_global_load_lds((__attribute__((address_space(1))) void*)(g),
                                   (__attribute__((address_space(3))) void*)(l),
                                   16, 0, 0);
}

// ---- job descriptors ---------------------------------------------------------------
struct GJ {   // GEMM job: C = A(M x K) * Bt(256 x K)^T, m97 structure
  const void* A0; int A0mode; int lda0;            // mode: 0 bf16 gld_lds, 1 f32 cvt
  const void* A1; int A1mode; int lda1; int K1;    // optional concat segment
  const void* Bt; int Btis32; int ldb;
  u16* P; int M; int nx; int kchunk;               // fused=0: bf16 partials -> P[bz]
  int fused;                                       // fused=1: epilogue below
  const float* bias; const u16* addmat; int do_relu;
  const float* resid; float* outf; u16* out16; u16* outT;
};
struct FJ {   // finalize job: out = sum_s P[s] * scale
  const u16* P; int S; int Mrows; float scale; float* out; u16* out16;
};

__device__ __forceinline__ GJ mkGP(const void* A0, int mode, int lda, const u16* Bt,
                                   int ldb, u16* Pr, int M, int K, int S) {
  GJ g; g.A0 = A0; g.A0mode = mode; g.lda0 = lda;
  g.A1 = nullptr; g.A1mode = 0; g.lda1 = 0; g.K1 = K;
  g.Bt = Bt; g.Btis32 = 0; g.ldb = ldb;
  g.P = Pr; g.M = M; g.nx = M / 128; g.kchunk = K / S; g.fused = 0;
  g.bias = nullptr; g.addmat = nullptr; g.do_relu = 0; g.resid = nullptr;
  g.outf = nullptr; g.out16 = nullptr; g.outT = nullptr;
  return g;
}
__device__ __forceinline__ GJ mkGF(const void* A0, int a0m, int lda0, const void* A1,
                                   int a1m, int lda1, int K1, const void* Bt, int bt32,
                                   int ldb, int M, int K, const float* bias,
                                   const u16* add, int relu, const float* resid,
                                   float* outf, u16* out16, u16* outT) {
  GJ g; g.A0 = A0; g.A0mode = a0m; g.lda0 = lda0;
  g.A1 = A1; g.A1mode = a1m; g.lda1 = lda1; g.K1 = K1;
  g.Bt = Bt; g.Btis32 = bt32; g.ldb = ldb;
  g.P = nullptr; g.M = M; g.nx = M / 128; g.kchunk = K; g.fused = 1;
  g.bias = bias; g.addmat = add; g.do_relu = relu; g.resid = resid;
  g.outf = outf; g.out16 = out16; g.outT = outT;
  return g;
}
__device__ __forceinline__ FJ mkFIN(const u16* Pr, int S, int M, float scale,
                                    float* out, u16* out16) {
  FJ f; f.P = Pr; f.S = S; f.Mrows = M; f.scale = scale; f.out = out; f.out16 = out16;
  return f;
}

// ---- GEMM device body (identical math to R13/R15), smem passed in -----------------
__device__ __forceinline__ void gemm_dev(const GJ& j, int bid, char* smbase)
{
  u16* As = (u16*)smbase;            // [2][8192] = 32 KB
  u16* Bs = (u16*)(smbase + 32768);  // [2][8192] = 32 KB

  __syncthreads();  // protect LDS reuse across grid-stride iterations / phases

  const int y = bid & 1;
  const int bx = (bid >> 1) % j.nx;
  const int bz = (bid >> 1) / j.nx;
  const int m0 = bx << 7;
  const int n0 = y << 7;
  const int kb = bz * j.kchunk;
  const int nkt = j.kchunk / GBK;

  const int tid = threadIdx.x;
  const int wid = tid >> 6;
  const int lane = tid & 63;
  const int wr = wid >> 1, wc = wid & 1;
  const int srow = lane >> 3;
  const int skk = (lane & 7) << 3;

  floatx4 acc[4][4];
  floatx4 zz = {0.f, 0.f, 0.f, 0.f};
#pragma unroll
  for (int i = 0; i < 4; ++i)
#pragma unroll
    for (int jj = 0; jj < 4; ++jj) acc[i][jj] = zz;

  auto stage = [&](int buf, int k0) {
    const void* base; int lda, mode, kl;
    if (k0 < j.K1) { base = j.A0; lda = j.lda0; mode = j.A0mode; kl = k0; }
    else           { base = j.A1; lda = j.lda1; mode = j.A1mode; kl = k0 - j.K1; }
    if (mode == 0) {
      const u16* U = (const u16*)base;
#pragma unroll
      for (int q = 0; q < 4; ++q) {
        int c = (wid << 2) + q;
        gld_lds16(U + (size_t)(m0 + (c << 3) + srow) * lda + kl + skk,
                  (void*)&As[buf * 8192 + (c << 9)]);
      }
    } else {
      const float* F = (const float*)base;
#pragma unroll
      for (int q = 0; q < 4; ++q) {
        int c = (wid << 2) + q;
        const size_t gi = (size_t)(m0 + (c << 3) + srow) * lda + kl + skk;
        floatx4 f0 = *(const floatx4*)(F + gi);
        floatx4 f1 = *(const floatx4*)(F + gi + 4);
        short8 v;
#pragma unroll
        for (int e = 0; e < 4; ++e) { v[e] = (short)f2bf(f0[e]); v[4 + e] = (short)f2bf(f1[e]); }
        *(short8*)&As[buf * 8192 + (c << 9) + (lane << 3)] = v;
      }
    }
    if (j.Btis32) {
      const float* F = (const float*)j.Bt;
#pragma unroll
      for (int q = 0; q < 4; ++q) {
        int c = (wid << 2) + q;
        const size_t gi = (size_t)(n0 + (c << 3) + srow) * j.ldb + k0 + skk;
        floatx4 f0 = *(const floatx4*)(F + gi);
        floatx4 f1 = *(const floatx4*)(F + gi + 4);
        short8 v;
#pragma unroll
        for (int e = 0; e < 4; ++e) { v[e] = (short)f2bf(f0[e]); v[4 + e] = (short)f2bf(f1[e]); }
        *(short8*)&Bs[buf * 8192 + (c << 9) + (lane << 3)] = v;
      }
    } else {
      const u16* U = (const u16*)j.Bt;
#pragma unroll
      for (int q = 0; q < 4; ++q) {
        int c = (wid << 2) + q;
        gld_lds16(U + (size_t)(n0 + (c << 3) + srow) * j.ldb + k0 + skk,
                  (void*)&Bs[buf * 8192 + (c << 9)]);
      }
    }
  };

  int cur = 0;
  stage(0, kb);
  for (int kt = 0; kt < nkt; ++kt) {
    __syncthreads();
    if (kt + 1 < nkt) stage(cur ^ 1, kb + (kt + 1) * GBK);
#pragma unroll
    for (int ks = 0; ks < 2; ++ks) {
      short8 a[4], b[4];
      const int ko = (ks << 5) + ((lane >> 4) << 3);
#pragma unroll
      for (int mi = 0; mi < 4; ++mi)
        a[mi] = *(const short8*)&As[cur * 8192 + ((wr << 6) + (mi << 4) + (lane & 15)) * GBK + ko];
#pragma unroll
      for (int ni = 0; ni < 4; ++ni)
        b[ni] = *(const short8*)&Bs[cur * 8192 + ((wc << 6) + (ni << 4) + (lane & 15)) * GBK + ko];
#pragma unroll
      for (int mi = 0; mi < 4; ++mi)
#pragma unroll
        for (int ni = 0; ni < 4; ++ni)
          acc[mi][ni] = __builtin_amdgcn_mfma_f32_16x16x32_bf16(a[mi], b[ni], acc[mi][ni], 0, 0, 0);
    }
    cur ^= 1;
  }

  if (j.fused) {
    u16* ts = (u16*)smbase;   // 128x128 u16 = 32 KB
    if (j.outT) __syncthreads();
#pragma unroll
    for (int mi = 0; mi < 4; ++mi) {
#pragma unroll
      for (int ni = 0; ni < 4; ++ni) {
        const int ml0 = (wr << 6) + (mi << 4) + ((lane >> 4) << 2);
        const int nl = (wc << 6) + (ni << 4) + (lane & 15);
        const int n = n0 + nl;
        const float bv = j.bias ? j.bias[n] : 0.f;
#pragma unroll
        for (int r = 0; r < 4; ++r) {
          const int ml = ml0 + r;
          const size_t idx = (size_t)(m0 + ml) * DIMN + n;
          float t = acc[mi][ni][r] + bv;
          if (j.addmat) t += bf2f(j.addmat[idx]);
          if (j.do_relu) t = fmaxf(t, 0.f);
          if (j.resid) t += j.resid[idx];
          if (j.outf) j.outf[idx] = t;
          const u16 q = f2bf(t);
          if (j.out16) j.out16[idx] = q;
          if (j.outT) ts[ml * 128 + (nl ^ ((ml & 7) << 3))] = q;
        }
      }
    }
    if (j.outT) {
      __syncthreads();
      const int nl = tid >> 1;
      const int mh = (tid & 1) << 6;
#pragma unroll
      for (int c8 = 0; c8 < 8; ++c8) {
        const int mB = mh + (c8 << 3);
        short8 v;
#pragma unroll
        for (int e = 0; e < 8; ++e)
          v[e] = (short)ts[(mB + e) * 128 + (nl ^ (((mB + e) & 7) << 3))];
        *(short8*)&j.outT[(size_t)(n0 + nl) * j.M + (m0 + mB)] = v;
      }
    }
  } else {
    u16* Pz = j.P + (size_t)bz * (size_t)j.M * DIMN;
#pragma unroll
    for (int mi = 0; mi < 4; ++mi) {
#pragma unroll
      for (int ni = 0; ni < 4; ++ni) {
        const int mb = m0 + (wr << 6) + (mi << 4) + ((lane >> 4) << 2);
        const int n = n0 + (wc << 6) + (ni << 4) + (lane & 15);
#pragma unroll
        for (int r = 0; r < 4; ++r)
          Pz[(size_t)(mb + r) * DIMN + n] = f2bf(acc[mi][ni][r]);
      }
    }
  }
}

__global__ __launch_bounds__(256, 2) void gemm1_k(GJ j0) {
  __shared__ __align__(16) char sm[65536];
  gemm_dev(j0, blockIdx.x, sm);
}
__global__ __launch_bounds__(256, 2) void gemm2_k(GJ j0, GJ j1, int nb0) {
  __shared__ __align__(16) char sm[65536];
  if ((int)blockIdx.x < nb0) gemm_dev(j0, blockIdx.x, sm);
  else                       gemm_dev(j1, blockIdx.x - nb0, sm);
}

// ---- finalize ----------------------------------------------------------------------
__device__ __forceinline__ void fin_dev(const FJ& f, int bid)
{
  const size_t MN = (size_t)f.Mrows * DIMN;
  const size_t i4 = (((size_t)bid << 8) + threadIdx.x) * 4;
  if (i4 >= MN) return;
  floatx4 v = {0.f, 0.f, 0.f, 0.f};
  for (int s = 0; s < f.S; ++s) {
    ushort4v p4 = *(const ushort4v*)(f.P + (size_t)s * MN + i4);
#pragma unroll
    for (int q = 0; q < 4; ++q) v[q] += bf2f(p4[q]);
  }
  floatx4 o;
#pragma unroll
  for (int q = 0; q < 4; ++q) o[q] = v[q] * f.scale;
  if (f.out) *(floatx4*)(f.out + i4) = o;
  if (f.out16) {
    unsigned long long qq = 0;
#pragma unroll
    for (int q = 0; q < 4; ++q) qq |= ((unsigned long long)f2bf(o[q])) << (16 * q);
    *(unsigned long long*)(f.out16 + i4) = qq;
  }
}
__global__ __launch_bounds__(256) void fin1_k(FJ f0) { fin_dev(f0, blockIdx.x); }
__global__ __launch_bounds__(256) void fin2_k(FJ f0, FJ f1, int nb0) {
  if ((int)blockIdx.x < nb0) fin_dev(f0, blockIdx.x);
  else                       fin_dev(f1, blockIdx.x - nb0);
}

// ---- fused finalize + transpose (x_d) ----------------------------------------------
__device__ __forceinline__ void fin_tr_dev(const u16* P, int S, int Mrows, float scale,
                                           float* outf, u16* outT, int ldT,
                                           char* smbase, int bx, int by)
{
  u16 (*t)[64] = (u16 (*)[64])smbase;   // 8 KB
  __syncthreads();
  const size_t MN = (size_t)Mrows * DIMN;
  const int r0 = bx << 6;
  const int c0 = by << 6;
  const int tid = threadIdx.x;
  const int lr = tid >> 3;
  const int lc = (tid & 7) << 3;
#pragma unroll
  for (int h = 0; h < 2; ++h) {
    const int r = lr + (h << 5);
    const size_t gi = (size_t)(r0 + r) * DIMN + (c0 + lc);
    float a[8];
#pragma unroll
    for (int e = 0; e < 8; ++e) a[e] = 0.f;
    for (int s = 0; s < S; ++s) {
      short8 p = *(const short8*)(P + (size_t)s * MN + gi);
#pragma unroll
      for (int e = 0; e < 8; ++e) a[e] += bf2f((u16)p[e]);
    }
    short8 v;
    floatx4 o0, o1;
#pragma unroll
    for (int e = 0; e < 4; ++e) {
      o0[e] = a[e] * scale; o1[e] = a[4 + e] * scale;
      v[e] = (short)f2bf(o0[e]); v[4 + e] = (short)f2bf(o1[e]);
    }
    *(floatx4*)(outf + gi) = o0;
    *(floatx4*)(outf + gi + 4) = o1;
    *(short8*)&t[r][lc ^ ((r >> 3) << 3)] = v;
  }
  __syncthreads();
#pragma unroll
  for (int h = 0; h < 2; ++h) {
    const int oc = lr + (h << 5);
    short8 v;
#pragma unroll
    for (int e = 0; e < 8; ++e)
      v[e] = (short)t[lc + e][oc ^ ((lc >> 3) << 3)];
    *(short8*)&outT[(size_t)(c0 + oc) * ldT + (r0 + lc)] = v;
  }
}
__global__ __launch_bounds__(256)
void finalize_tr_k(const u16* __restrict__ P, int S, int Mrows, float scale,
                   float* __restrict__ outf, u16* __restrict__ outT, int ldT)
{
  __shared__ __align__(16) char sm[8192];
  fin_tr_dev(P, S, Mrows, scale, outf, outT, ldT, sm, blockIdx.x, blockIdx.y);
}

// ---- transpose ---------------------------------------------------------------------
__device__ __forceinline__ void transpose_dev(const void* in, int is32, int ldin,
                                              u16* out, int ldout, u16* copy16,
                                              int bx, int by, char* smbase)
{
  u16 (*t)[64] = (u16 (*)[64])smbase;
  const int c0 = bx << 6;
  const int r0 = by << 6;
  const int tid = threadIdx.x;
  const int lr = tid >> 3;
  const int lc = (tid & 7) << 3;
#pragma unroll
  for (int h = 0; h < 2; ++h) {
    const int r = lr + (h << 5);
    short8 v;
    if (is32) {
      const float* F = (const float*)in;
      const size_t gi = (size_t)(r0 + r) * ldin + (c0 + lc);
      floatx4 f0 = *(const floatx4*)(F + gi);
      floatx4 f1 = *(const floatx4*)(F + gi + 4);
#pragma unroll
      for (int e = 0; e < 4; ++e) { v[e] = (short)f2bf(f0[e]); v[4 + e] = (short)f2bf(f1[e]); }
      if (copy16) *(short8*)(copy16 + gi) = v;
    } else {
      v = *(const short8*)((const u16*)in + (size_t)(r0 + r) * ldin + (c0 + lc));
    }
    *(short8*)&t[r][lc ^ ((r >> 3) << 3)] = v;
  }
  __syncthreads();
#pragma unroll
  for (int h = 0; h < 2; ++h) {
    const int oc = lr + (h << 5);
    short8 v;
#pragma unroll
    for (int e = 0; e < 8; ++e)
      v[e] = (short)t[lc + e][oc ^ ((lc >> 3) << 3)];
    *(short8*)&out[(size_t)(c0 + oc) * ldout + (r0 + lc)] = v;
  }
}
__global__ __launch_bounds__(256)
void transpose_k(const void* __restrict__ in, int is32, int ldin,
                 u16* __restrict__ out, int ldout, u16* __restrict__ copy16)
{
  __shared__ __align__(16) char sm[8192];
  transpose_dev(in, is32, ldin, out, ldout, copy16, blockIdx.x, blockIdx.y, sm);
}

// ---- mega-prep (fixed decode, unchanged from R15) ----------------------------------
__device__ __forceinline__ void cvt_dev(const float* in, u16* out, size_t n,
                                        int bid, int nb)
{
  const size_t stride = (size_t)nb * 2048;
  for (size_t i = (((size_t)bid << 8) + threadIdx.x) << 3; i < n; i += stride) {
    floatx4 f0 = *(const floatx4*)(in + i);
    floatx4 f1 = *(const floatx4*)(in + i + 4);
    short8 v;
#pragma unroll
    for (int e = 0; e < 4; ++e) { v[e] = (short)f2bf(f0[e]); v[4 + e] = (short)f2bf(f1[e]); }
    *(short8*)(out + i) = v;
  }
}
__global__ __launch_bounds__(256)
void prep_k(const float* __restrict__ Ad, u16* __restrict__ Ad16,
            const float* __restrict__ Ap, u16* __restrict__ Ap16,
            const float* __restrict__ A, u16* __restrict__ At16, u16* __restrict__ A16,
            const float* __restrict__ primal, u16* __restrict__ XTp,
            float* __restrict__ pouts)
{
  __shared__ __align__(16) char sm[8192];
  const int bid = blockIdx.x;
  if (bid < 2048) {
    cvt_dev(Ad, Ad16, (size_t)kNF * kNF, bid, 2048);
  } else if (bid < 3072) {
    cvt_dev(Ap, Ap16, (size_t)kNV * kNV, bid - 2048, 1024);
  } else if (bid < 21504) {
    const int t = bid - 3072;      // A: C=kNF (192 x-tiles), R=kNV (96 y-tiles)
    transpose_dev(A, 1, kNF, At16, kNV, A16, t % 192, t / 192, sm);
  } else if (bid < 21888) {
    const int t = bid - 21504;     // primal: C=256 (4), R=kNV (96)
    transpose_dev(primal, 1, DIMN, XTp, kNV, nullptr, t % 4, t / 4, sm);
  } else {
    const int t = bid - 21888;     // copy primal -> pouts (768 blocks)
    const size_t i = (((size_t)t << 8) + threadIdx.x) << 3;
    *(floatx4*)(pouts + i) = *(const floatx4*)(primal + i);
    *(floatx4*)(pouts + i + 4) = *(const floatx4*)(primal + i + 4);
  }
}

// ---- fused face gather + transpose -------------------------------------------------
__device__ __forceinline__ void face_dev(const float* xp, const float* xd,
                                         const int* faces, u16* f, u16* fT,
                                         char* smbase, int bid)
{
  u16 (*tile)[DIMN + 8] = (u16 (*)[DIMN + 8])smbase;   // 33792 B
  __syncthreads();
  const int fi0 = bid << 6;
  const int jj = threadIdx.x;
  for (int k = 0; k < 64; ++k) {
    const int fi = fi0 + k;
    const int a = faces[fi * 3 + 0];
    const int b = faces[fi * 3 + 1];
    const int c = faces[fi * 3 + 2];
    const float xv = xd[(size_t)fi * DIMN + jj];
    const float s = fabsf(xp[(size_t)a * DIMN + jj] - xv)
                  + fabsf(xp[(size_t)b * DIMN + jj] - xv)
                  + fabsf(xp[(size_t)c * DIMN + jj] - xv);
    const u16 q = f2bf(s * (1.0f / 3.0f));
    f[(size_t)fi * DIMN + jj] = q;
    tile[k][jj] = q;
  }
  __syncthreads();
#pragma unroll
  for (int c8 = 0; c8 < 8; ++c8) {
    short8 v;
#pragma unroll
    for (int e = 0; e < 8; ++e) v[e] = (short)tile[(c8 << 3) + e][jj];
    *(short8*)&fT[(size_t)jj * kNF + fi0 + (c8 << 3)] = v;
  }
}
__global__ __launch_bounds__(256)
void face_gather_tr_k(const float* __restrict__ xp, const float* __restrict__ xd,
                      const int* __restrict__ faces, u16* __restrict__ f,
                      u16* __restrict__ fT)
{
  __shared__ __align__(16) char sm[33792];
  face_dev(xp, xd, faces, f, fT, sm, blockIdx.x);
}

// ---- cooperative mega-kernel: all post-prep phases with grid.sync ------------------
struct MegaArgs {
  const u16 *Ad16, *Ap16, *At16, *A16;
  u16 *XTp, *XTd, *TBd, *TBp, *t1d, *t1p, *fcd, *fcp;
  float *xp3, *xd3;
  u16 *Pd, *Pp;
  const float *pW, *pb, *pgW, *pgb, *dW, *db, *dgW, *dgb, *Wp, *bp, *Wd, *bd;
  const int* faces;
  const float* primal;
  float *pouts, *douts, *out0, *out1;
};

__global__ __launch_bounds__(256, 2) void mega_k(MegaArgs a)
{
  __shared__ __align__(16) char sm[65536];
  cg::grid_group grid = cg::this_grid();
  const int nb = (int)gridDim.x;
  const size_t NVD = (size_t)kNV * DIMN, NFD = (size_t)kNF * DIMN;

  auto gsync = [&]() { __threadfence(); grid.sync(); };

  // ph0: x_d partials = At16 @ XTp -> Pd (S=4), 768 vb
  for (int vb = blockIdx.x; vb < 768; vb += nb)
    gemm_dev(mkGP(a.At16, 0, kNV, a.XTp, kNV, a.Pd, kNF, kNV, 4), vb, sm);
  gsync();
  // ph1: finalize_tr -> douts + XTd, 192 x 4 tiles
  for (int vb = blockIdx.x; vb < 768; vb += nb)
    fin_tr_dev(a.Pd, 4, kNF, 1.0f / 3.0f, a.douts, a.XTd, kNF, sm, vb % 192, vb / 192);
  gsync();

  const float* xdc = a.douts;
  const float* xpc = a.primal;
  for (int i = 0; i < 3; ++i) {
    const float* dWi = a.dW + (size_t)i * 65536;
    const float* dgWi = a.dgW + (size_t)i * 65536;
    const float* pWi = a.pW + (size_t)i * 65536;
    const float* pgWi = a.pgW + (size_t)i * 65536;
    const float* dbi = a.db + i * 256;
    const float* dgbi = a.dgb + i * 256;
    const float* pbi = a.pb + i * 256;
    const float* pgbi = a.pgb + i * 256;

    // G1: Ad@Xd (768) + Ap@Xp (768)
    for (int vb = blockIdx.x; vb < 1536; vb += nb) {
      if (vb < 768) gemm_dev(mkGP(a.Ad16, 0, kNF, a.XTd, kNF, a.Pd, kNF, kNF, 4), vb, sm);
      else          gemm_dev(mkGP(a.Ap16, 0, kNV, a.XTp, kNV, a.Pp, kNV, kNV, 8), vb - 768, sm);
    }
    gsync();
    // F1: dual 3072 + primal 1536
    for (int vb = blockIdx.x; vb < 4608; vb += nb) {
      if (vb < 3072) fin_dev(mkFIN(a.Pd, 4, kNF, 1.f, nullptr, a.t1d), vb);
      else           fin_dev(mkFIN(a.Pp, 8, kNV, 1.f, nullptr, a.t1p), vb - 3072);
    }
    gsync();
    // W1: fc + fc^T (dual 192 + primal 96)
    for (int vb = blockIdx.x; vb < 288; vb += nb) {
      if (vb < 192)
        gemm_dev(mkGF(a.t1d, 0, 256, nullptr, 0, 0, 256, dWi, 1, 256, kNF, 256,
                      dbi, nullptr, 0, nullptr, nullptr, a.fcd, a.TBd), vb, sm);
      else
        gemm_dev(mkGF(a.t1p, 0, 256, nullptr, 0, 0, 256, pWi, 1, 256, kNV, 256,
                      pbi, nullptr, 0, nullptr, nullptr, a.fcp, a.TBp), vb - 192, sm);
    }
    gsync();
    // G2: Ad@fc_d + Ap@fc_p
    for (int vb = blockIdx.x; vb < 1536; vb += nb) {
      if (vb < 768) gemm_dev(mkGP(a.Ad16, 0, kNF, a.TBd, kNF, a.Pd, kNF, kNF, 4), vb, sm);
      else          gemm_dev(mkGP(a.Ap16, 0, kNV, a.TBp, kNV, a.Pp, kNV, kNV, 8), vb - 768, sm);
    }
    gsync();
    // F2
    for (int vb = blockIdx.x; vb < 4608; vb += nb) {
      if (vb < 3072) fin_dev(mkFIN(a.Pd, 4, kNF, 1.f, nullptr, a.t1d), vb);
      else           fin_dev(mkFIN(a.Pp, 8, kNV, 1.f, nullptr, a.t1p), vb - 3072);
    }
    gsync();
    // W2: relu(fc+og)+x -> next x (+x^T)
    float* nxd = (i < 2) ? (a.douts + (size_t)(i + 1) * NFD) : a.xd3;
    float* nxp = (i < 2) ? (a.pouts + (size_t)(i + 1) * NVD) : a.xp3;
    u16* xdT = (i < 2) ? a.XTd : nullptr;
    u16* xpT = (i < 2) ? a.XTp : nullptr;
    for (int vb = blockIdx.x; vb < 288; vb += nb) {
      if (vb < 192)
        gemm_dev(mkGF(a.t1d, 0, 256, nullptr, 0, 0, 256, dgWi, 1, 256, kNF, 256,
                      dgbi, a.fcd, 1, xdc, nxd, nullptr, xdT), vb, sm);
      else
        gemm_dev(mkGF(a.t1p, 0, 256, nullptr, 0, 0, 256, pgWi, 1, 256, kNV, 256,
                      pgbi, a.fcp, 1, xpc, nxp, nullptr, xpT), vb - 192, sm);
    }
    gsync();
    xdc = nxd; xpc = nxp;
  }

  // face gather + f^T (192 vb)
  for (int vb = blockIdx.x; vb < 192; vb += nb)
    face_dev(a.xp3, a.xd3, a.faces, a.t1d, a.TBd, sm, vb);
  gsync();
  // out_dual GF (192) + mapped GP (768)
  for (int vb = blockIdx.x; vb < 960; vb += nb) {
    if (vb < 192)
      gemm_dev(mkGF(a.xd3, 1, 256, a.t1d, 0, 256, 256, a.Wd, 1, 512, kNF, 512,
                    a.bd, nullptr, 1, a.xd3, a.out1, nullptr, nullptr), vb, sm);
    else
      gemm_dev(mkGP(a.A16, 0, kNF, a.TBd, kNF, a.Pp, kNV, kNF, 8), vb - 192, sm);
  }
  gsync();
  // fin mapped -> fcp (1536 vb)
  for (int vb = blockIdx.x; vb < 1536; vb += nb)
    fin_dev(mkFIN(a.Pp, 8, kNV, 1.f, nullptr, a.fcp), vb);
  gsync();
  // final W: out_primal (96 vb)
  for (int vb = blockIdx.x; vb < 96; vb += nb)
    gemm_dev(mkGF(a.xp3, 1, 256, a.fcp, 0, 256, 256, a.Wp, 1, 512, kNV, 512,
                  a.bp, nullptr, 1, a.xp3, a.out0, nullptr, nullptr), vb, sm);
}

extern "C" void kernel_launch(void* const* d_in, const int* in_sizes, int n_in,
                              void* d_out, int out_size, void* d_ws, size_t ws_size,
                              hipStream_t stream)
{
  (void)in_sizes; (void)n_in; (void)out_size;
  const float* primal   = (const float*)d_in[0];
  const float* A_primal = (const float*)d_in[1];
  const float* A_dual   = (const float*)d_in[2];
  const float* A        = (const float*)d_in[3];
  const int* faces      = (const int*)d_in[4];
  const float* pW  = (const float*)d_in[5];
  const float* pb  = (const float*)d_in[6];
  const float* pgW = (const float*)d_in[7];
  const float* pgb = (const float*)d_in[8];
  const float* dW  = (const float*)d_in[9];
  const float* db  = (const float*)d_in[10];
  const float* dgW = (const float*)d_in[11];
  const float* dgb = (const float*)d_in[12];
  const float* Wp  = (const float*)d_in[13];
  const float* bp  = (const float*)d_in[14];
  const float* Wd  = (const float*)d_in[15];
  const float* bd  = (const float*)d_in[16];

  char* wsp = (char*)d_ws;
  auto alloc = [&](size_t bytes) -> void* {
    void* p = (void*)wsp;
    wsp += (bytes + 255) & ~(size_t)255;
    return p;
  };
  const size_t NVD = (size_t)kNV * DIMN, NFD = (size_t)kNF * DIMN;
  u16* XTp   = (u16*)alloc(NVD * 2);
  u16* XTd   = (u16*)alloc(NFD * 2);
  u16* TBd   = (u16*)alloc(NFD * 2);
  u16* TBp   = (u16*)alloc(NVD * 2);
  u16* t1d   = (u16*)alloc(NFD * 2);
  u16* t1p   = (u16*)alloc(NVD * 2);
  u16* fcd   = (u16*)alloc(NFD * 2);
  u16* fcp   = (u16*)alloc(NVD * 2);
  float* xp3 = (float*)alloc(NVD * 4);
  float* xd3 = (float*)alloc(NFD * 4);
  u16* P     = (u16*)alloc((size_t)8 * NFD * 2);
  u16* Pd    = P;
  u16* Pp    = P + 4 * NFD;
  const size_t bigElems = (size_t)kNF * kNF + 2 * (size_t)kNF * kNV + (size_t)kNV * kNV;
  const size_t need = (size_t)(wsp - (char*)d_ws) + bigElems * 2 + 4096;
  const bool big = ws_size >= need;
  u16 *Ad16 = nullptr, *At16 = nullptr, *A16 = nullptr, *Ap16 = nullptr;
  if (big) {
    Ad16 = (u16*)alloc((size_t)kNF * kNF * 2);
    At16 = (u16*)alloc((size_t)kNF * kNV * 2);
    A16  = (u16*)alloc((size_t)kNV * kNF * 2);
    Ap16 = (u16*)alloc((size_t)kNV * kNV * 2);
  }

  float* out0  = (float*)d_out;
  float* out1  = out0 + NVD;
  float* pouts = out1 + NFD;
  float* douts = pouts + 3 * NVD;

  // ---- prep (one launch, big path) ----
  if (big) {
    prep_k<<<dim3(22656), dim3(256), 0, stream>>>(
        A_dual, Ad16, A_primal, Ap16, A, At16, A16, primal, XTp, pouts);
  }

  // ---- try cooperative mega-kernel ----
  bool useMega = false;
  if (big) {
    MegaArgs ma;
    ma.Ad16 = Ad16; ma.Ap16 = Ap16; ma.At16 = At16; ma.A16 = A16;
    ma.XTp = XTp; ma.XTd = XTd; ma.TBd = TBd; ma.TBp = TBp;
    ma.t1d = t1d; ma.t1p = t1p; ma.fcd = fcd; ma.fcp = fcp;
    ma.xp3 = xp3; ma.xd3 = xd3; ma.Pd = Pd; ma.Pp = Pp;
    ma.pW = pW; ma.pb = pb; ma.pgW = pgW; ma.pgb = pgb;
    ma.dW = dW; ma.db = db; ma.dgW = dgW; ma.dgb = dgb;
    ma.Wp = Wp; ma.bp = bp; ma.Wd = Wd; ma.bd = bd;
    ma.faces = faces; ma.primal = primal;
    ma.pouts = pouts; ma.douts = douts; ma.out0 = out0; ma.out1 = out1;
    int maxb = 0;
    if (hipOccupancyMaxActiveBlocksPerMultiprocessor(&maxb, mega_k, 256, 0)
            == hipSuccess && maxb >= 1) {
      const int nblk = (maxb >= 2 ? 512 : 256);
      void* kp[1] = { &ma };
      if (hipLaunchCooperativeKernel((void*)mega_k, dim3(nblk), dim3(256),
                                     kp, 0, stream) == hipSuccess)
        useMega = true;
    }
  }

  if (!useMega) {
    // ---- classic R15 sequence (verified fallback) ----
    auto GP = [&](const void* A0, int mode, int lda, const u16* Bt, int ldb,
                  u16* Pr, int M, int K, int S) -> GJ {
      GJ g{}; g.A0 = A0; g.A0mode = mode; g.lda0 = lda;
      g.A1 = nullptr; g.A1mode = 0; g.lda1 = 0; g.K1 = K;
      g.Bt = Bt; g.Btis32 = 0; g.ldb = ldb;
      g.P = Pr; g.M = M; g.nx = M / 128; g.kchunk = K / S; g.fused = 0;
      g.bias = nullptr; g.addmat = nullptr; g.do_relu = 0; g.resid = nullptr;
      g.outf = nullptr; g.out16 = nullptr; g.outT = nullptr;
      return g;
    };
    auto GF = [&](const void* A0, int a0m, int lda0, const void* A1, int a1m,
                  int lda1, int K1, const void* Bt, int bt32, int ldb, int M, int K,
                  const float* bias, const u16* add, int relu, const float* resid,
                  float* outf, u16* out16, u16* outT) -> GJ {
      GJ g{}; g.A0 = A0; g.A0mode = a0m; g.lda0 = lda0;
      g.A1 = A1; g.A1mode = a1m; g.lda1 = lda1; g.K1 = K1;
      g.Bt = Bt; g.Btis32 = bt32; g.ldb = ldb;
      g.P = P; g.M = M; g.nx = M / 128; g.kchunk = K; g.fused = 1;
      g.bias = bias; g.addmat = add; g.do_relu = relu; g.resid = resid;
      g.outf = outf; g.out16 = out16; g.outT = outT;
      return g;
    };
    auto gblk = [&](const GJ& g) { return g.nx * 2 * (g.fused ? 1 : (g.K1 / g.kchunk)); };
    auto launch2 = [&](const GJ& aj, const GJ& bj) {
      const int nb0 = gblk(aj);
      gemm2_k<<<dim3(nb0 + gblk(bj)), dim3(256), 0, stream>>>(aj, bj, nb0);
    };
    auto launch1 = [&](const GJ& aj) {
      gemm1_k<<<dim3(gblk(aj)), dim3(256), 0, stream>>>(aj);
    };
    auto FIN = [&](const u16* Pr, int S, int M, float scale, float* out, u16* out16) -> FJ {
      FJ f{}; f.P = Pr; f.S = S; f.Mrows = M; f.scale = scale; f.out = out; f.out16 = out16;
      return f;
    };
    auto fblk = [&](const FJ& f) { return (int)((size_t)f.Mrows * DIMN / 1024); };
    auto fin2 = [&](const FJ& aj, const FJ& bj) {
      const int nb0 = fblk(aj);
      fin2_k<<<dim3(nb0 + fblk(bj)), dim3(256), 0, stream>>>(aj, bj, nb0);
    };
    auto fin1 = [&](const FJ& aj) { fin1_k<<<dim3(fblk(aj)), dim3(256), 0, stream>>>(aj); };
    auto tranp = [&](const void* in, int is32, int ldin, u16* out, int ldout,
                     int R, int C, u16* copy16) {
      transpose_k<<<dim3(C / 64, R / 64), dim3(256), 0, stream>>>(
          in, is32, ldin, out, ldout, copy16);
    };

    if (!big) {
      tranp(primal, 1, DIMN, XTp, kNV, kNV, DIMN, nullptr);
      hipMemcpyAsync(pouts, primal, NVD * 4, hipMemcpyDeviceToDevice, stream);
    }

    const void* ApP = big ? (const void*)Ap16 : (const void*)A_primal;
    const int apm = big ? 0 : 1;
    const void* AdP = big ? (const void*)Ad16 : (const void*)A_dual;
    const int adm = big ? 0 : 1;

    if (big) {
      launch1(GP(At16, 0, kNV, XTp, kNV, Pd, kNF, kNV, 4));
      finalize_tr_k<<<dim3(kNF / 64, 4), dim3(256), 0, stream>>>(
          Pd, 4, kNF, 1.0f / 3.0f, douts, XTd, kNF);
    } else {
      for (int s = 0; s < kNF / SLAB; ++s) {
        const int m0 = s * SLAB;
        tranp(A + m0, 1, kNF, TBd, kNV, kNV, SLAB, nullptr);
        launch1(GP(TBd, 0, kNV, XTp, kNV, Pd, SLAB, kNV, 16));
        fin1(FIN(Pd, 16, SLAB, 1.0f / 3.0f, douts + (size_t)m0 * DIMN, nullptr));
      }
      tranp(douts, 1, DIMN, XTd, kNF, kNF, DIMN, nullptr);
    }

    const float* xpc = primal;
    const float* xdc = douts;
    for (int i = 0; i < 3; ++i) {
      launch2(GP(AdP, adm, kNF, XTd, kNF, Pd, kNF, kNF, 4),
              GP(ApP, apm, kNV, XTp, kNV, Pp, kNV, kNV, 8));
      fin2(FIN(Pd, 4, kNF, 1.f, nullptr, t1d), FIN(Pp, 8, kNV, 1.f, nullptr, t1p));
      launch2(GF(t1d, 0, 256, nullptr, 0, 0, 256, dW + (size_t)i * 65536, 1, 256,
                 kNF, 256, db + i * 256, nullptr, 0, nullptr, nullptr, fcd, TBd),
              GF(t1p, 0, 256, nullptr, 0, 0, 256, pW + (size_t)i * 65536, 1, 256,
                 kNV, 256, pb + i * 256, nullptr, 0, nullptr, nullptr, fcp, TBp));
      launch2(GP(AdP, adm, kNF, TBd, kNF, Pd, kNF, kNF, 4),
              GP(ApP, apm, kNV, TBp, kNV, Pp, kNV, kNV, 8));
      fin2(FIN(Pd, 4, kNF, 1.f, nullptr, t1d), FIN(Pp, 8, kNV, 1.f, nullptr, t1p));
      float* nxd = (i < 2) ? (douts + (size_t)(i + 1) * NFD) : xd3;
      float* nxp = (i < 2) ? (pouts + (size_t)(i + 1) * NVD) : xp3;
      u16* xdT = (i < 2) ? XTd : nullptr;
      u16* xpT = (i < 2) ? XTp : nullptr;
      launch2(GF(t1d, 0, 256, nullptr, 0, 0, 256, dgW + (size_t)i * 65536, 1, 256,
                 kNF, 256, dgb + i * 256, fcd, 1, xdc, nxd, nullptr, xdT),
              GF(t1p, 0, 256, nullptr, 0, 0, 256, pgW + (size_t)i * 65536, 1, 256,
                 kNV, 256, pgb + i * 256, fcp, 1, xpc, nxp, nullptr, xpT));
      xdc = nxd; xpc = nxp;
    }

    face_gather_tr_k<<<dim3(kNF / 64), dim3(256), 0, stream>>>(
        xp3, xd3, faces, t1d, TBd);
    {
      GJ jo = GF(xd3, 1, 256, t1d, 0, 256, 256, Wd, 1, 512, kNF, 512,
                 bd, nullptr, 1, xd3, out1, nullptr, nullptr);
      GJ jm = big ? GP(A16, 0, kNF, TBd, kNF, Pp, kNV, kNF, 8)
                  : GP(A, 1, kNF, TBd, kNF, Pp, kNV, kNF, 8);
      launch2(jo, jm);
    }
    fin1(FIN(Pp, 8, kNV, 1.f, nullptr, fcp));
    launch1(GF(xp3, 1, 256, fcp, 0, 256, 256, Wp, 1, 512, kNV, 512,
               bp, nullptr, 1, xp3, out0, nullptr, nullptr));
  }
}

// Round 17
// 1799.694 us; speedup vs baseline: 2.0067x; 2.0067x over previous
//
#include <hip/hip_runtime.h>

// TwoStreamNet on MI355X — f32 I/O, bf16 MFMA internals.
// R17: revert to the proven R13/R15 configuration (best measured: 1799 us).
//      Per-launch kernels, two-job merged dispatches, mega-prep (fixed decode),
//      fused face_gather+transpose. No cooperative path (R16 regressed 2x).

typedef short short8 __attribute__((ext_vector_type(8)));
typedef float floatx4 __attribute__((ext_vector_type(4)));
typedef unsigned short ushort4v __attribute__((ext_vector_type(4)));
typedef unsigned short u16;

#define DIMN 256
#define GBK 64

static const int kNV = 6144;
static const int kNF = 12288;
static const int SLAB = 768;

__device__ __forceinline__ float bf2f(u16 u) {
  union { unsigned int i; float f; } x; x.i = ((unsigned int)u) << 16; return x.f;
}
__device__ __forceinline__ u16 f2bf(float f) {
  union { float f; unsigned int i; } x; x.f = f;
  unsigned int r = x.i + 0x7fffu + ((x.i >> 16) & 1u);
  return (u16)(r >> 16);
}
__device__ __forceinline__ void gld_lds16(const void* g, void* l) {
  __builtin_amdgcn_global_load_lds((__attribute__((address_space(1))) void*)(g),
                                   (__attribute__((address_space(3))) void*)(l),
                                   16, 0, 0);
}

// ---- job descriptors ---------------------------------------------------------------
struct GJ {   // GEMM job: C = A(M x K) * Bt(256 x K)^T, m97 structure
  const void* A0; int A0mode; int lda0;            // mode: 0 bf16 gld_lds, 1 f32 cvt
  const void* A1; int A1mode; int lda1; int K1;    // optional concat segment
  const void* Bt; int Btis32; int ldb;
  u16* P; int M; int nx; int kchunk;               // fused=0: bf16 partials -> P[bz]
  int fused;                                       // fused=1: epilogue below
  const float* bias; const u16* addmat; int do_relu;
  const float* resid; float* outf; u16* out16; u16* outT;
};
struct FJ {   // finalize job: out = sum_s P[s] * scale
  const u16* P; int S; int Mrows; float scale; float* out; u16* out16;
};

// ---- GEMM device body (identical math to R13) --------------------------------------
__device__ __forceinline__ void gemm_dev(const GJ& j, int bid)
{
  __shared__ __align__(16) u16 As[2][128 * GBK];
  __shared__ __align__(16) u16 Bs[2][128 * GBK];

  const int y = bid & 1;
  const int bx = (bid >> 1) % j.nx;
  const int bz = (bid >> 1) / j.nx;
  const int m0 = bx << 7;
  const int n0 = y << 7;
  const int kb = bz * j.kchunk;
  const int nkt = j.kchunk / GBK;

  const int tid = threadIdx.x;
  const int wid = tid >> 6;
  const int lane = tid & 63;
  const int wr = wid >> 1, wc = wid & 1;
  const int srow = lane >> 3;
  const int skk = (lane & 7) << 3;

  floatx4 acc[4][4];
  floatx4 zz = {0.f, 0.f, 0.f, 0.f};
#pragma unroll
  for (int i = 0; i < 4; ++i)
#pragma unroll
    for (int jj = 0; jj < 4; ++jj) acc[i][jj] = zz;

  auto stage = [&](int buf, int k0) {
    const void* base; int lda, mode, kl;
    if (k0 < j.K1) { base = j.A0; lda = j.lda0; mode = j.A0mode; kl = k0; }
    else           { base = j.A1; lda = j.lda1; mode = j.A1mode; kl = k0 - j.K1; }
    if (mode == 0) {
      const u16* U = (const u16*)base;
#pragma unroll
      for (int q = 0; q < 4; ++q) {
        int c = (wid << 2) + q;
        gld_lds16(U + (size_t)(m0 + (c << 3) + srow) * lda + kl + skk,
                  (void*)&As[buf][c << 9]);
      }
    } else {
      const float* F = (const float*)base;
#pragma unroll
      for (int q = 0; q < 4; ++q) {
        int c = (wid << 2) + q;
        const size_t gi = (size_t)(m0 + (c << 3) + srow) * lda + kl + skk;
        floatx4 f0 = *(const floatx4*)(F + gi);
        floatx4 f1 = *(const floatx4*)(F + gi + 4);
        short8 v;
#pragma unroll
        for (int e = 0; e < 4; ++e) { v[e] = (short)f2bf(f0[e]); v[4 + e] = (short)f2bf(f1[e]); }
        *(short8*)&As[buf][(c << 9) + (lane << 3)] = v;
      }
    }
    if (j.Btis32) {
      const float* F = (const float*)j.Bt;
#pragma unroll
      for (int q = 0; q < 4; ++q) {
        int c = (wid << 2) + q;
        const size_t gi = (size_t)(n0 + (c << 3) + srow) * j.ldb + k0 + skk;
        floatx4 f0 = *(const floatx4*)(F + gi);
        floatx4 f1 = *(const floatx4*)(F + gi + 4);
        short8 v;
#pragma unroll
        for (int e = 0; e < 4; ++e) { v[e] = (short)f2bf(f0[e]); v[4 + e] = (short)f2bf(f1[e]); }
        *(short8*)&Bs[buf][(c << 9) + (lane << 3)] = v;
      }
    } else {
      const u16* U = (const u16*)j.Bt;
#pragma unroll
      for (int q = 0; q < 4; ++q) {
        int c = (wid << 2) + q;
        gld_lds16(U + (size_t)(n0 + (c << 3) + srow) * j.ldb + k0 + skk,
                  (void*)&Bs[buf][c << 9]);
      }
    }
  };

  int cur = 0;
  stage(0, kb);
  for (int kt = 0; kt < nkt; ++kt) {
    __syncthreads();
    if (kt + 1 < nkt) stage(cur ^ 1, kb + (kt + 1) * GBK);
#pragma unroll
    for (int ks = 0; ks < 2; ++ks) {
      short8 a[4], b[4];
      const int ko = (ks << 5) + ((lane >> 4) << 3);
#pragma unroll
      for (int mi = 0; mi < 4; ++mi)
        a[mi] = *(const short8*)&As[cur][((wr << 6) + (mi << 4) + (lane & 15)) * GBK + ko];
#pragma unroll
      for (int ni = 0; ni < 4; ++ni)
        b[ni] = *(const short8*)&Bs[cur][((wc << 6) + (ni << 4) + (lane & 15)) * GBK + ko];
#pragma unroll
      for (int mi = 0; mi < 4; ++mi)
#pragma unroll
        for (int ni = 0; ni < 4; ++ni)
          acc[mi][ni] = __builtin_amdgcn_mfma_f32_16x16x32_bf16(a[mi], b[ni], acc[mi][ni], 0, 0, 0);
    }
    cur ^= 1;
  }

  if (j.fused) {
    u16* ts = (u16*)&As[0][0];
    if (j.outT) __syncthreads();
#pragma unroll
    for (int mi = 0; mi < 4; ++mi) {
#pragma unroll
      for (int ni = 0; ni < 4; ++ni) {
        const int ml0 = (wr << 6) + (mi << 4) + ((lane >> 4) << 2);
        const int nl = (wc << 6) + (ni << 4) + (lane & 15);
        const int n = n0 + nl;
        const float bv = j.bias ? j.bias[n] : 0.f;
#pragma unroll
        for (int r = 0; r < 4; ++r) {
          const int ml = ml0 + r;
          const size_t idx = (size_t)(m0 + ml) * DIMN + n;
          float t = acc[mi][ni][r] + bv;
          if (j.addmat) t += bf2f(j.addmat[idx]);
          if (j.do_relu) t = fmaxf(t, 0.f);
          if (j.resid) t += j.resid[idx];
          if (j.outf) j.outf[idx] = t;
          const u16 q = f2bf(t);
          if (j.out16) j.out16[idx] = q;
          if (j.outT) ts[ml * 128 + (nl ^ ((ml & 7) << 3))] = q;
        }
      }
    }
    if (j.outT) {
      __syncthreads();
      const int nl = tid >> 1;
      const int mh = (tid & 1) << 6;
#pragma unroll
      for (int c8 = 0; c8 < 8; ++c8) {
        const int mB = mh + (c8 << 3);
        short8 v;
#pragma unroll
        for (int e = 0; e < 8; ++e)
          v[e] = (short)ts[(mB + e) * 128 + (nl ^ (((mB + e) & 7) << 3))];
        *(short8*)&j.outT[(size_t)(n0 + nl) * j.M + (m0 + mB)] = v;
      }
    }
  } else {
    u16* Pz = j.P + (size_t)bz * (size_t)j.M * DIMN;
#pragma unroll
    for (int mi = 0; mi < 4; ++mi) {
#pragma unroll
      for (int ni = 0; ni < 4; ++ni) {
        const int mb = m0 + (wr << 6) + (mi << 4) + ((lane >> 4) << 2);
        const int n = n0 + (wc << 6) + (ni << 4) + (lane & 15);
#pragma unroll
        for (int r = 0; r < 4; ++r)
          Pz[(size_t)(mb + r) * DIMN + n] = f2bf(acc[mi][ni][r]);
      }
    }
  }
}

__global__ __launch_bounds__(256, 2) void gemm1_k(GJ j0) { gemm_dev(j0, blockIdx.x); }
__global__ __launch_bounds__(256, 2) void gemm2_k(GJ j0, GJ j1, int nb0) {
  if ((int)blockIdx.x < nb0) gemm_dev(j0, blockIdx.x);
  else                       gemm_dev(j1, blockIdx.x - nb0);
}

// ---- finalize ----------------------------------------------------------------------
__device__ __forceinline__ void fin_dev(const FJ& f, int bid)
{
  const size_t MN = (size_t)f.Mrows * DIMN;
  const size_t i4 = (((size_t)bid << 8) + threadIdx.x) * 4;
  if (i4 >= MN) return;
  floatx4 v = {0.f, 0.f, 0.f, 0.f};
  for (int s = 0; s < f.S; ++s) {
    ushort4v p4 = *(const ushort4v*)(f.P + (size_t)s * MN + i4);
#pragma unroll
    for (int q = 0; q < 4; ++q) v[q] += bf2f(p4[q]);
  }
  floatx4 o;
#pragma unroll
  for (int q = 0; q < 4; ++q) o[q] = v[q] * f.scale;
  if (f.out) *(floatx4*)(f.out + i4) = o;
  if (f.out16) {
    unsigned long long qq = 0;
#pragma unroll
    for (int q = 0; q < 4; ++q) qq |= ((unsigned long long)f2bf(o[q])) << (16 * q);
    *(unsigned long long*)(f.out16 + i4) = qq;
  }
}
__global__ __launch_bounds__(256) void fin1_k(FJ f0) { fin_dev(f0, blockIdx.x); }
__global__ __launch_bounds__(256) void fin2_k(FJ f0, FJ f1, int nb0) {
  if ((int)blockIdx.x < nb0) fin_dev(f0, blockIdx.x);
  else                       fin_dev(f1, blockIdx.x - nb0);
}

// ---- fused finalize + transpose (x_d): sum S slabs *scale -> outf + outT ----------
__global__ __launch_bounds__(256)
void finalize_tr_k(const u16* __restrict__ P, int S, int Mrows, float scale,
                   float* __restrict__ outf, u16* __restrict__ outT, int ldT)
{
  __shared__ __align__(16) u16 t[64][64];
  const size_t MN = (size_t)Mrows * DIMN;
  const int r0 = blockIdx.x << 6;
  const int c0 = blockIdx.y << 6;
  const int tid = threadIdx.x;
  const int lr = tid >> 3;
  const int lc = (tid & 7) << 3;
#pragma unroll
  for (int h = 0; h < 2; ++h) {
    const int r = lr + (h << 5);
    const size_t gi = (size_t)(r0 + r) * DIMN + (c0 + lc);
    float a[8];
#pragma unroll
    for (int e = 0; e < 8; ++e) a[e] = 0.f;
    for (int s = 0; s < S; ++s) {
      short8 p = *(const short8*)(P + (size_t)s * MN + gi);
#pragma unroll
      for (int e = 0; e < 8; ++e) a[e] += bf2f((u16)p[e]);
    }
    short8 v;
    floatx4 o0, o1;
#pragma unroll
    for (int e = 0; e < 4; ++e) {
      o0[e] = a[e] * scale; o1[e] = a[4 + e] * scale;
      v[e] = (short)f2bf(o0[e]); v[4 + e] = (short)f2bf(o1[e]);
    }
    *(floatx4*)(outf + gi) = o0;
    *(floatx4*)(outf + gi + 4) = o1;
    *(short8*)&t[r][lc ^ ((r >> 3) << 3)] = v;
  }
  __syncthreads();
#pragma unroll
  for (int h = 0; h < 2; ++h) {
    const int oc = lr + (h << 5);
    short8 v;
#pragma unroll
    for (int e = 0; e < 8; ++e)
      v[e] = (short)t[lc + e][oc ^ ((lc >> 3) << 3)];
    *(short8*)&outT[(size_t)(c0 + oc) * ldT + (r0 + lc)] = v;
  }
}

// ---- transpose device body (f32/bf16 in, bf16 out; optional straight copy) --------
__device__ __forceinline__ void transpose_dev(const void* in, int is32, int ldin,
                                              u16* out, int ldout, u16* copy16,
                                              int bx, int by)
{
  __shared__ __align__(16) u16 t[64][64];
  const int c0 = bx << 6;
  const int r0 = by << 6;
  const int tid = threadIdx.x;
  const int lr = tid >> 3;
  const int lc = (tid & 7) << 3;
#pragma unroll
  for (int h = 0; h < 2; ++h) {
    const int r = lr + (h << 5);
    short8 v;
    if (is32) {
      const float* F = (const float*)in;
      const size_t gi = (size_t)(r0 + r) * ldin + (c0 + lc);
      floatx4 f0 = *(const floatx4*)(F + gi);
      floatx4 f1 = *(const floatx4*)(F + gi + 4);
#pragma unroll
      for (int e = 0; e < 4; ++e) { v[e] = (short)f2bf(f0[e]); v[4 + e] = (short)f2bf(f1[e]); }
      if (copy16) *(short8*)(copy16 + gi) = v;
    } else {
      v = *(const short8*)((const u16*)in + (size_t)(r0 + r) * ldin + (c0 + lc));
    }
    *(short8*)&t[r][lc ^ ((r >> 3) << 3)] = v;
  }
  __syncthreads();
#pragma unroll
  for (int h = 0; h < 2; ++h) {
    const int oc = lr + (h << 5);
    short8 v;
#pragma unroll
    for (int e = 0; e < 8; ++e)
      v[e] = (short)t[lc + e][oc ^ ((lc >> 3) << 3)];
    *(short8*)&out[(size_t)(c0 + oc) * ldout + (r0 + lc)] = v;
  }
}

__global__ __launch_bounds__(256)
void transpose_k(const void* __restrict__ in, int is32, int ldin,
                 u16* __restrict__ out, int ldout, u16* __restrict__ copy16)
{
  transpose_dev(in, is32, ldin, out, ldout, copy16, blockIdx.x, blockIdx.y);
}

// ---- mega-prep: cvt(Ad) | cvt(Ap) | tranp(A -> At16 + A16) | tranp(primal) | copy --
// block ranges: [0,2048) [2048,3072) [3072,21504) [21504,21888) [21888,22656)
__device__ __forceinline__ void cvt_dev(const float* in, u16* out, size_t n,
                                        int bid, int nb)
{
  const size_t stride = (size_t)nb * 2048;
  for (size_t i = (((size_t)bid << 8) + threadIdx.x) << 3; i < n; i += stride) {
    floatx4 f0 = *(const floatx4*)(in + i);
    floatx4 f1 = *(const floatx4*)(in + i + 4);
    short8 v;
#pragma unroll
    for (int e = 0; e < 4; ++e) { v[e] = (short)f2bf(f0[e]); v[4 + e] = (short)f2bf(f1[e]); }
    *(short8*)(out + i) = v;
  }
}
__global__ __launch_bounds__(256)
void prep_k(const float* __restrict__ Ad, u16* __restrict__ Ad16,
            const float* __restrict__ Ap, u16* __restrict__ Ap16,
            const float* __restrict__ A, u16* __restrict__ At16, u16* __restrict__ A16,
            const float* __restrict__ primal, u16* __restrict__ XTp,
            float* __restrict__ pouts)
{
  const int bid = blockIdx.x;
  if (bid < 2048) {
    cvt_dev(Ad, Ad16, (size_t)kNF * kNF, bid, 2048);
  } else if (bid < 3072) {
    cvt_dev(Ap, Ap16, (size_t)kNV * kNV, bid - 2048, 1024);
  } else if (bid < 21504) {
    // tranp A (kNV x kNF): C = kNF -> 192 x-tiles, R = kNV -> 96 y-tiles
    const int t = bid - 3072;
    transpose_dev(A, 1, kNF, At16, kNV, A16, t % 192, t / 192);
  } else if (bid < 21888) {
    const int t = bid - 21504;                 // tranp primal: C=256 (4), R=kNV (96)
    transpose_dev(primal, 1, DIMN, XTp, kNV, nullptr, t % 4, t / 4);
  } else {
    const int t = bid - 21888;                 // copy primal -> pouts (768 blocks)
    const size_t i = (((size_t)t << 8) + threadIdx.x) << 3;
    *(floatx4*)(pouts + i) = *(const floatx4*)(primal + i);
    *(floatx4*)(pouts + i + 4) = *(const floatx4*)(primal + i + 4);
  }
}

// ---- fused face gather + transpose: f[fi][j] and fT[j][fi] ------------------------
__global__ __launch_bounds__(256)
void face_gather_tr_k(const float* __restrict__ xp, const float* __restrict__ xd,
                      const int* __restrict__ faces, u16* __restrict__ f,
                      u16* __restrict__ fT)
{
  __shared__ u16 tile[64][DIMN + 8];
  const int fi0 = blockIdx.x << 6;
  const int jj = threadIdx.x;
  for (int k = 0; k < 64; ++k) {
    const int fi = fi0 + k;
    const int a = faces[fi * 3 + 0];
    const int b = faces[fi * 3 + 1];
    const int c = faces[fi * 3 + 2];
    const float xv = xd[(size_t)fi * DIMN + jj];
    const float s = fabsf(xp[(size_t)a * DIMN + jj] - xv)
                  + fabsf(xp[(size_t)b * DIMN + jj] - xv)
                  + fabsf(xp[(size_t)c * DIMN + jj] - xv);
    const u16 q = f2bf(s * (1.0f / 3.0f));
    f[(size_t)fi * DIMN + jj] = q;
    tile[k][jj] = q;
  }
  __syncthreads();
#pragma unroll
  for (int c8 = 0; c8 < 8; ++c8) {
    short8 v;
#pragma unroll
    for (int e = 0; e < 8; ++e) v[e] = (short)tile[(c8 << 3) + e][jj];
    *(short8*)&fT[(size_t)jj * kNF + fi0 + (c8 << 3)] = v;
  }
}

extern "C" void kernel_launch(void* const* d_in, const int* in_sizes, int n_in,
                              void* d_out, int out_size, void* d_ws, size_t ws_size,
                              hipStream_t stream)
{
  (void)in_sizes; (void)n_in; (void)out_size;
  const float* primal   = (const float*)d_in[0];
  const float* A_primal = (const float*)d_in[1];
  const float* A_dual   = (const float*)d_in[2];
  const float* A        = (const float*)d_in[3];
  const int* faces      = (const int*)d_in[4];
  const float* pW  = (const float*)d_in[5];
  const float* pb  = (const float*)d_in[6];
  const float* pgW = (const float*)d_in[7];
  const float* pgb = (const float*)d_in[8];
  const float* dW  = (const float*)d_in[9];
  const float* db  = (const float*)d_in[10];
  const float* dgW = (const float*)d_in[11];
  const float* dgb = (const float*)d_in[12];
  const float* Wp  = (const float*)d_in[13];
  const float* bp  = (const float*)d_in[14];
  const float* Wd  = (const float*)d_in[15];
  const float* bd  = (const float*)d_in[16];

  char* wsp = (char*)d_ws;
  auto alloc = [&](size_t bytes) -> void* {
    void* p = (void*)wsp;
    wsp += (bytes + 255) & ~(size_t)255;
    return p;
  };
  const size_t NVD = (size_t)kNV * DIMN, NFD = (size_t)kNF * DIMN;
  u16* XTp   = (u16*)alloc(NVD * 2);                 // x_p^T [256][6144]
  u16* XTd   = (u16*)alloc(NFD * 2);                 // x_d^T [256][12288]
  u16* TBd   = (u16*)alloc(NFD * 2);                 // dual fc^T / f^T
  u16* TBp   = (u16*)alloc(NVD * 2);                 // primal fc^T
  u16* t1d   = (u16*)alloc(NFD * 2);                 // dual Adj@X sum / face f
  u16* t1p   = (u16*)alloc(NVD * 2);                 // primal Adj@X sum
  u16* fcd   = (u16*)alloc(NFD * 2);                 // dual out_fc
  u16* fcp   = (u16*)alloc(NVD * 2);                 // primal out_fc / mapped
  float* xp3 = (float*)alloc(NVD * 4);               // final x_p
  float* xd3 = (float*)alloc(NFD * 4);               // final x_d
  u16* P     = (u16*)alloc((size_t)8 * NFD * 2);     // partials: dual 4xNFD | primal 8xNVD
  u16* Pd    = P;
  u16* Pp    = P + 4 * NFD;
  const size_t bigElems = (size_t)kNF * kNF + 2 * (size_t)kNF * kNV + (size_t)kNV * kNV;
  const size_t need = (size_t)(wsp - (char*)d_ws) + bigElems * 2 + 4096;
  const bool big = ws_size >= need;
  u16 *Ad16 = nullptr, *At16 = nullptr, *A16 = nullptr, *Ap16 = nullptr;
  if (big) {
    Ad16 = (u16*)alloc((size_t)kNF * kNF * 2);
    At16 = (u16*)alloc((size_t)kNF * kNV * 2);
    A16  = (u16*)alloc((size_t)kNV * kNF * 2);
    Ap16 = (u16*)alloc((size_t)kNV * kNV * 2);
  }

  float* out0  = (float*)d_out;      // out_primal + x_p
  float* out1  = out0 + NVD;         // out_dual + x_d
  float* pouts = out1 + NFD;         // primal_outs x3 (f32)
  float* douts = pouts + 3 * NVD;    // dual_outs x3 (f32)

  auto GP = [&](const void* A0, int mode, int lda, const u16* Bt, int ldb,
                u16* Pr, int M, int K, int S) -> GJ {
    GJ g{}; g.A0 = A0; g.A0mode = mode; g.lda0 = lda;
    g.A1 = nullptr; g.A1mode = 0; g.lda1 = 0; g.K1 = K;
    g.Bt = Bt; g.Btis32 = 0; g.ldb = ldb;
    g.P = Pr; g.M = M; g.nx = M / 128; g.kchunk = K / S; g.fused = 0;
    g.bias = nullptr; g.addmat = nullptr; g.do_relu = 0; g.resid = nullptr;
    g.outf = nullptr; g.out16 = nullptr; g.outT = nullptr;
    return g;
  };
  auto GF = [&](const void* A0, int a0m, int lda0, const void* A1, int a1m,
                int lda1, int K1, const void* Bt, int bt32, int ldb, int M, int K,
                const float* bias, const u16* add, int relu, const float* resid,
                float* outf, u16* out16, u16* outT) -> GJ {
    GJ g{}; g.A0 = A0; g.A0mode = a0m; g.lda0 = lda0;
    g.A1 = A1; g.A1mode = a1m; g.lda1 = lda1; g.K1 = K1;
    g.Bt = Bt; g.Btis32 = bt32; g.ldb = ldb;
    g.P = P; g.M = M; g.nx = M / 128; g.kchunk = K; g.fused = 1;
    g.bias = bias; g.addmat = add; g.do_relu = relu; g.resid = resid;
    g.outf = outf; g.out16 = out16; g.outT = outT;
    return g;
  };
  auto gblk = [&](const GJ& g) { return g.nx * 2 * (g.fused ? 1 : (g.K1 / g.kchunk)); };
  auto launch2 = [&](const GJ& a, const GJ& b) {
    const int nb0 = gblk(a);
    gemm2_k<<<dim3(nb0 + gblk(b)), dim3(256), 0, stream>>>(a, b, nb0);
  };
  auto launch1 = [&](const GJ& a) {
    gemm1_k<<<dim3(gblk(a)), dim3(256), 0, stream>>>(a);
  };
  auto FIN = [&](const u16* Pr, int S, int M, float scale, float* out, u16* out16) -> FJ {
    FJ f{}; f.P = Pr; f.S = S; f.Mrows = M; f.scale = scale; f.out = out; f.out16 = out16;
    return f;
  };
  auto fblk = [&](const FJ& f) { return (int)((size_t)f.Mrows * DIMN / 1024); };
  auto fin2 = [&](const FJ& a, const FJ& b) {
    const int nb0 = fblk(a);
    fin2_k<<<dim3(nb0 + fblk(b)), dim3(256), 0, stream>>>(a, b, nb0);
  };
  auto fin1 = [&](const FJ& a) { fin1_k<<<dim3(fblk(a)), dim3(256), 0, stream>>>(a); };
  auto tranp = [&](const void* in, int is32, int ldin, u16* out, int ldout,
                   int R, int C, u16* copy16) {
    transpose_k<<<dim3(C / 64, R / 64), dim3(256), 0, stream>>>(
        in, is32, ldin, out, ldout, copy16);
  };

  // ---- one-time prep: ONE launch for cvt+cvt+tranp(A)+tranp(primal)+copy ----
  if (big) {
    prep_k<<<dim3(22656), dim3(256), 0, stream>>>(
        A_dual, Ad16, A_primal, Ap16, A, At16, A16, primal, XTp, pouts);
  } else {
    tranp(primal, 1, DIMN, XTp, kNV, kNV, DIMN, nullptr);
    hipMemcpyAsync(pouts, primal, NVD * 4, hipMemcpyDeviceToDevice, stream);
  }

  const void* ApP = big ? (const void*)Ap16 : (const void*)A_primal;
  const int apm = big ? 0 : 1;
  const void* AdP = big ? (const void*)Ad16 : (const void*)A_dual;
  const int adm = big ? 0 : 1;

  // ---- x_d = (1/3) A^T @ primal -> douts[0] (f32) + XTd ----
  if (big) {
    launch1(GP(At16, 0, kNV, XTp, kNV, Pd, kNF, kNV, 4));
    finalize_tr_k<<<dim3(kNF / 64, 4), dim3(256), 0, stream>>>(
        Pd, 4, kNF, 1.0f / 3.0f, douts, XTd, kNF);
  } else {
    for (int s = 0; s < kNF / SLAB; ++s) {
      const int m0 = s * SLAB;
      tranp(A + m0, 1, kNF, TBd, kNV, kNV, SLAB, nullptr);
      launch1(GP(TBd, 0, kNV, XTp, kNV, Pd, SLAB, kNV, 16));
      fin1(FIN(Pd, 16, SLAB, 1.0f / 3.0f, douts + (size_t)m0 * DIMN, nullptr));
    }
    tranp(douts, 1, DIMN, XTd, kNF, kNF, DIMN, nullptr);
  }

  // ---- AGG layers: primal+dual merged per step ----
  const float* xpc = primal;
  const float* xdc = douts;
  for (int i = 0; i < 3; ++i) {
    // G1: Ad@Xd (768 blk) + Ap@Xp (768 blk)
    launch2(GP(AdP, adm, kNF, XTd, kNF, Pd, kNF, kNF, 4),
            GP(ApP, apm, kNV, XTp, kNV, Pp, kNV, kNV, 8));
    // F1
    fin2(FIN(Pd, 4, kNF, 1.f, nullptr, t1d), FIN(Pp, 8, kNV, 1.f, nullptr, t1p));
    // W1: fc_d + fc_d^T ; fc_p + fc_p^T
    launch2(GF(t1d, 0, 256, nullptr, 0, 0, 256, dW + (size_t)i * 65536, 1, 256,
               kNF, 256, db + i * 256, nullptr, 0, nullptr, nullptr, fcd, TBd),
            GF(t1p, 0, 256, nullptr, 0, 0, 256, pW + (size_t)i * 65536, 1, 256,
               kNV, 256, pb + i * 256, nullptr, 0, nullptr, nullptr, fcp, TBp));
    // G2: Ad@fc_d + Ap@fc_p
    launch2(GP(AdP, adm, kNF, TBd, kNF, Pd, kNF, kNF, 4),
            GP(ApP, apm, kNV, TBp, kNV, Pp, kNV, kNV, 8));
    // F2
    fin2(FIN(Pd, 4, kNF, 1.f, nullptr, t1d), FIN(Pp, 8, kNV, 1.f, nullptr, t1p));
    // W2: relu(fc+og)+x -> next x (+x^T)
    float* nxd = (i < 2) ? (douts + (size_t)(i + 1) * NFD) : xd3;
    float* nxp = (i < 2) ? (pouts + (size_t)(i + 1) * NVD) : xp3;
    u16* xdT = (i < 2) ? XTd : nullptr;
    u16* xpT = (i < 2) ? XTp : nullptr;
    launch2(GF(t1d, 0, 256, nullptr, 0, 0, 256, dgW + (size_t)i * 65536, 1, 256,
               kNF, 256, dgb + i * 256, fcd, 1, xdc, nxd, nullptr, xdT),
            GF(t1p, 0, 256, nullptr, 0, 0, 256, pgW + (size_t)i * 65536, 1, 256,
               kNV, 256, pgb + i * 256, fcp, 1, xpc, nxp, nullptr, xpT));
    xdc = nxd; xpc = nxp;
  }

  // ---- PDF ----
  face_gather_tr_k<<<dim3(kNF / 64), dim3(256), 0, stream>>>(
      xp3, xd3, faces, t1d, TBd);                                 // f + f^T fused
  // [out_dual GEMM (192 blk)] + [mapped = A @ f -> Pp (768 blk)] merged
  {
    GJ jo = GF(xd3, 1, 256, t1d, 0, 256, 256, Wd, 1, 512, kNF, 512,
               bd, nullptr, 1, xd3, out1, nullptr, nullptr);
    GJ jm = big ? GP(A16, 0, kNF, TBd, kNF, Pp, kNV, kNF, 8)
                : GP(A, 1, kNF, TBd, kNF, Pp, kNV, kNF, 8);
    launch2(jo, jm);
  }
  fin1(FIN(Pp, 8, kNV, 1.f, nullptr, fcp));                       // mapped
  // out_primal = relu([x_p, mapped] @ Wp^T + bp) + x_p
  launch1(GF(xp3, 1, 256, fcp, 0, 256, 256, Wp, 1, 512, kNV, 512,
             bp, nullptr, 1, xp3, out0, nullptr, nullptr));
}